// Round 8
// baseline (789.229 us; speedup 1.0000x reference)
//
#include <hip/hip_runtime.h>
#include <math.h>

#define B 128
#define D 128
#define NMEM 100000
#define KTOT 8194
#define NEGK 8192
#define NREF (B * KTOT)  // 1,048,832
#define CHUNKS 16
#define CS 513  // ceil(8194/16)
#define N4 (NMEM * D / 4)  // 3,200,000 float4 per mem array

#define ROWS_PER_BLK 64
#define NBLK_MAIN ((NMEM + ROWS_PER_BLK - 1) / ROWS_PER_BLK)  // 1563

// ---- workspace layout (bytes) for the inverted-index path ----
#define WS_CNT 0u                      // u32[100000] counts, then scatter cursors
#define WS_START 400000u               // u32[100001] row starts
#define WS_ENTRIES 800016u             // u32[NREF]
#define WS_PARTIALS 4995344u           // float[128*12]
#define WS_SP 5001488u                 // float[128*6]
#define WS_NEED 5004560u

// plain vector type for nontemporal builtins (HIP_vector_type is rejected)
typedef float nt4 __attribute__((ext_vector_type(4)));

// =====================================================================
// Inverted-index path: sort references by row, stream each row once.
// =====================================================================

__global__ void zero_k(unsigned* __restrict__ cnt, float* __restrict__ partials_g,
                       float* __restrict__ sp_g) {
    const int i = blockIdx.x * 256 + threadIdx.x;
    if (i < NMEM) cnt[i] = 0u;
    if (i < 128 * 12) partials_g[i] = 0.f;
    if (i < 128 * 6) sp_g[i] = 0.f;
}

__global__ void hist_k(const int* __restrict__ pos_idx, const int* __restrict__ neg_idx,
                       unsigned* __restrict__ cnt) {
    const int b = blockIdx.y;
    const int k = blockIdx.x * 256 + threadIdx.x;
    if (k >= KTOT) return;
    const int r = (k < 2) ? pos_idx[b * 2 + k] : neg_idx[b * NEGK + k - 2];
    atomicAdd(&cnt[r], 1u);
}

#define SCAN_PER 98  // ceil(100000/1024)
__global__ __launch_bounds__(1024) void scan_k(const unsigned* __restrict__ cnt,
                                               unsigned* __restrict__ start,
                                               unsigned* __restrict__ ofs) {
    __shared__ unsigned lds[1024];
    const int t = threadIdx.x;
    const int base = t * SCAN_PER;
    unsigned sum = 0;
    for (int i = 0; i < SCAN_PER; ++i) {
        const int idx = base + i;
        if (idx < NMEM) sum += cnt[idx];
    }
    lds[t] = sum;
    __syncthreads();
    // Hillis-Steele inclusive scan over 1024 partials
    for (int off = 1; off < 1024; off <<= 1) {
        const unsigned v = (t >= off) ? lds[t - off] : 0u;
        __syncthreads();
        lds[t] += v;
        __syncthreads();
    }
    unsigned run = (t == 0) ? 0u : lds[t - 1];
    for (int i = 0; i < SCAN_PER; ++i) {
        const int idx = base + i;
        if (idx < NMEM) {
            start[idx] = run;
            ofs[idx] = run;
            run += cnt[idx];
        }
    }
    if (t == 0) start[NMEM] = NREF;
}

__global__ void scatter_k(const int* __restrict__ pos_idx, const int* __restrict__ neg_idx,
                          unsigned* __restrict__ ofs, unsigned* __restrict__ entries) {
    const int b = blockIdx.y;
    const int k = blockIdx.x * 256 + threadIdx.x;
    if (k >= KTOT) return;
    const int r = (k < 2) ? pos_idx[b * 2 + k] : neg_idx[b * NEGK + k - 2];
    const unsigned p = atomicAdd(&ofs[r], 1u);
    entries[p] = ((unsigned)b << 14) | (unsigned)k;  // b:7b | k:14b
}

// Main: block owns 64 rows; wave w handles rows w, w+4, ... Each group of 8
// lanes holds the full row pair in regs; 8 refs processed per wave-iter
// against the L2-hot 128 KB emb tables. Per-b sums via LDS atomics, one
// global atomicAdd pass per block at the end.
__global__ __launch_bounds__(256) void main_gather(
        const float* __restrict__ emb0, const float* __restrict__ emb1,
        const float* __restrict__ mem0, const float* __restrict__ mem1,
        const unsigned* __restrict__ start, const unsigned* __restrict__ entries,
        float* __restrict__ partials_g, float* __restrict__ sp_g) {
    const int tid = threadIdx.x;
    const int lane = tid & 63;
    const int w = tid >> 6;
    const int g = lane >> 3;
    const int l8 = lane & 7;
    const float INV_TAU = 1.0f / 0.07f;
    const float INV3 = 1.0f / 3.0f;

    __shared__ float accum[128][12];
    for (int i = tid; i < 128 * 12; i += 256) ((float*)accum)[i] = 0.f;
    __syncthreads();

    const int n0 = blockIdx.x * ROWS_PER_BLK;
    for (int rr = w; rr < ROWS_PER_BLK; rr += 4) {
        const int n = n0 + rr;
        if (n >= NMEM) break;
        const unsigned s0 = start[n], s1 = start[n + 1];
        if (s0 == s1) continue;
        float4 r0[4], r1[4];
        #pragma unroll
        for (int j = 0; j < 4; ++j) {
            r0[j] = *(const float4*)(mem0 + n * D + j * 32 + l8 * 4);
            r1[j] = *(const float4*)(mem1 + n * D + j * 32 + l8 * 4);
        }
        for (unsigned e = s0; e < s1; e += 8) {
            const unsigned ei = e + g;
            const bool act = (ei < s1);
            const unsigned ent = entries[act ? ei : (s1 - 1)];
            const int b = (int)(ent >> 14);
            const int k = (int)(ent & 0x3FFFu);
            float pij = 0.f, pii = 0.f, pji = 0.f, pjj = 0.f;
            #pragma unroll
            for (int j = 0; j < 4; ++j) {
                const float4 q0 = *(const float4*)(emb0 + b * D + j * 32 + l8 * 4);
                const float4 q1 = *(const float4*)(emb1 + b * D + j * 32 + l8 * 4);
                pij += r0[j].x * q1.x + r0[j].y * q1.y + r0[j].z * q1.z + r0[j].w * q1.w;
                pii += r0[j].x * q0.x + r0[j].y * q0.y + r0[j].z * q0.z + r0[j].w * q0.w;
                pji += r1[j].x * q0.x + r1[j].y * q0.y + r1[j].z * q0.z + r1[j].w * q0.w;
                pjj += r1[j].x * q1.x + r1[j].y * q1.y + r1[j].z * q1.z + r1[j].w * q1.w;
            }
            #pragma unroll
            for (int off = 1; off < 8; off <<= 1) {
                pij += __shfl_xor(pij, off, 64);
                pii += __shfl_xor(pii, off, 64);
                pji += __shfl_xor(pji, off, 64);
                pjj += __shfl_xor(pjj, off, 64);
            }
            if (act && l8 == 0) {
                const float cij = pij * INV_TAU, ci0 = pii * INV_TAU;
                const float cji = pji * INV_TAU, ci1 = pjj * INV_TAU;
                const float e3ij = __expf(cij * INV3), e3ji = __expf(cji * INV3);
                atomicAdd(&accum[b][0], __expf(cij));
                atomicAdd(&accum[b][1], __expf(cji));
                atomicAdd(&accum[b][4], e3ij);
                atomicAdd(&accum[b][5], e3ji);
                atomicAdd(&accum[b][8], e3ji * (cji - cij));
                atomicAdd(&accum[b][9], e3ij * (cij - cji));
                if (k >= 1) {
                    const float e3i0 = __expf(ci0 * INV3), e3i1 = __expf(ci1 * INV3);
                    atomicAdd(&accum[b][2], __expf(ci0));
                    atomicAdd(&accum[b][3], __expf(ci1));
                    atomicAdd(&accum[b][6], e3i0);
                    atomicAdd(&accum[b][7], e3i1);
                    atomicAdd(&accum[b][10], e3i1 * (ci1 - ci0));
                    atomicAdd(&accum[b][11], e3i0 * (ci0 - ci1));
                }
                if (k == 0) { sp_g[b * 6 + 0] = cij; sp_g[b * 6 + 2] = cji; }
                else if (k == 1) { sp_g[b * 6 + 1] = cij; sp_g[b * 6 + 3] = cji;
                                   sp_g[b * 6 + 4] = ci0; sp_g[b * 6 + 5] = ci1; }
            }
        }
    }
    __syncthreads();
    for (int i = tid; i < 128 * 12; i += 256) {
        const float v = ((float*)accum)[i];
        if (v != 0.f) atomicAdd(&partials_g[i], v);
    }
}

// Merged finalize + update_rows for the inverted path.
__global__ void final2(const float* __restrict__ partials_g, const float* __restrict__ sp_g,
                       float* __restrict__ out,
                       const float* __restrict__ emb0, const float* __restrict__ emb1,
                       const float* __restrict__ mem0, const float* __restrict__ mem1,
                       const int* __restrict__ pos_idx,
                       float* __restrict__ o0, float* __restrict__ o1) {
    if (blockIdx.x < B) {
        const int b = blockIdx.x;
        const int tid = threadIdx.x;  // 128
        const int lane = tid & 63;
        const int net = tid >> 6;
        const int p0 = pos_idx[b * 2];
        bool skip = false;
        for (int b2 = b + 1; b2 < B; ++b2)
            if (pos_idx[b2 * 2] == p0) skip = true;  // numpy scatter: last write wins
        if (skip) return;
        const float* mem = net ? mem1 : mem0;
        const float* emb = net ? emb1 : emb0;
        float* o = net ? o1 : o0;
        const float2 mv = *(const float2*)(mem + p0 * D + 2 * lane);
        const float2 ev = *(const float2*)(emb + b * D + 2 * lane);
        const float ux = 0.5f * mv.x + 0.5f * ev.x;
        const float uy = 0.5f * mv.y + 0.5f * ev.y;
        float ss = ux * ux + uy * uy;
        #pragma unroll
        for (int off = 1; off < 64; off <<= 1) ss += __shfl_xor(ss, off, 64);
        const float inv = 1.0f / sqrtf(ss);
        float2 wv; wv.x = ux * inv; wv.y = uy * inv;
        *(float2*)(o + p0 * D + 2 * lane) = wv;
        return;
    }
    const int b = threadIdx.x;
    float a[12];
    #pragma unroll
    for (int j = 0; j < 12; ++j) a[j] = partials_g[b * 12 + j];
    const float* e = sp_g + b * 6;
    const float cij0 = e[0], cij1 = e[1], cji0 = e[2], cji1 = e[3], i01 = e[4], i11 = e[5];
    const float icl_b = -((cij0 + cij1) * 0.5f - __logf(a[0]))
                        - ((cji0 + cji1) * 0.5f - __logf(a[1]));
    const float vcl_b = -(i01 - __logf(a[2])) - (i11 - __logf(a[3]));
    const float sicl_b = 3.0f * (a[8] / a[5] + a[9] / a[4]);
    const float svcl_b = 3.0f * (a[10] / a[7] + a[11] / a[6]);
    __shared__ float r[4][128];
    r[0][b] = vcl_b; r[1][b] = svcl_b; r[2][b] = icl_b; r[3][b] = sicl_b;
    __syncthreads();
    for (int s = 64; s > 0; s >>= 1) {
        if (b < s) {
            r[0][b] += r[0][b + s]; r[1][b] += r[1][b + s];
            r[2][b] += r[2][b + s]; r[3][b] += r[3][b + s];
        }
        __syncthreads();
    }
    if (b == 0) {
        out[0] = r[0][0] * (1.0f / 128.f);
        out[1] = r[1][0] * (1.0f / 128.f);
        out[2] = r[2][0] * (1.0f / 128.f);
        out[3] = r[3][0] * (1.0f / 128.f);
    }
}

// =====================================================================
// Fallback path (exact round-7 kernels) for small workspaces.
// =====================================================================

__global__ __launch_bounds__(256, 4) void gather_logits(
        const float* __restrict__ emb0, const float* __restrict__ emb1,
        const float* __restrict__ mem0, const float* __restrict__ mem1,
        const int* __restrict__ pos_idx, const int* __restrict__ neg_idx,
        float* __restrict__ partials) {
    const int c = blockIdx.x;
    const int b = blockIdx.y;
    const int tid = threadIdx.x;
    const int lane = tid & 63;
    const int w = tid >> 6;
    const int g = lane >> 3;
    const int l8 = lane & 7;
    const float INV_TAU = 1.0f / 0.07f;
    const float INV3 = 1.0f / 3.0f;

    float4 q0[4], q1[4];
    #pragma unroll
    for (int j = 0; j < 4; ++j) {
        q0[j] = *(const float4*)(emb0 + b * D + j * 32 + l8 * 4);
        q1[j] = *(const float4*)(emb1 + b * D + j * 32 + l8 * 4);
    }

    float s1ij = 0.f, s1ji = 0.f, s1i0 = 0.f, s1i1 = 0.f;
    float s3ij = 0.f, s3ji = 0.f, s3i0 = 0.f, s3i1 = 0.f;
    float wa = 0.f, wb = 0.f, wc = 0.f, wd = 0.f;

    __shared__ float red[4][12];
    __shared__ float sps[6];

    const int k0 = c * CS;
    const int kend = (k0 + CS < KTOT) ? k0 + CS : KTOT;
    const int kbase = k0 + w * 8 + g;
    const int posbase = b * 2;
    const int negbase = b * NEGK - 2;

    if (tid < 6) sps[tid] = 0.f;

    float4 A0[4], A1[4], B0[4], B1[4];

#define FETCH(IT, R0, R1) do {                                               \
    const int kf = kbase + (IT) * 32;                                        \
    const int kc = (kf < kend) ? kf : (kend - 1);                            \
    const int r = (kc < 2) ? pos_idx[posbase + kc] : neg_idx[negbase + kc];  \
    const float* p0 = mem0 + r * D + l8 * 4;                                 \
    const float* p1 = mem1 + r * D + l8 * 4;                                 \
    _Pragma("unroll")                                                        \
    for (int j = 0; j < 4; ++j) {                                            \
        R0[j] = *(const float4*)(p0 + j * 32);                               \
        R1[j] = *(const float4*)(p1 + j * 32);                               \
    }                                                                        \
} while (0)

#define COMPUTE(IT, R0, R1) do {                                             \
    const int kk = kbase + (IT) * 32;                                        \
    float pij = 0.f, pii = 0.f, pji = 0.f, pjj = 0.f;                        \
    _Pragma("unroll")                                                        \
    for (int j = 0; j < 4; ++j) {                                            \
        pij += R0[j].x * q1[j].x + R0[j].y * q1[j].y                         \
             + R0[j].z * q1[j].z + R0[j].w * q1[j].w;                        \
        pii += R0[j].x * q0[j].x + R0[j].y * q0[j].y                         \
             + R0[j].z * q0[j].z + R0[j].w * q0[j].w;                        \
        pji += R1[j].x * q0[j].x + R1[j].y * q0[j].y                         \
             + R1[j].z * q0[j].z + R1[j].w * q0[j].w;                        \
        pjj += R1[j].x * q1[j].x + R1[j].y * q1[j].y                         \
             + R1[j].z * q1[j].z + R1[j].w * q1[j].w;                        \
    }                                                                        \
    _Pragma("unroll")                                                        \
    for (int off = 1; off < 8; off <<= 1) {                                  \
        pij += __shfl_xor(pij, off, 64);                                     \
        pii += __shfl_xor(pii, off, 64);                                     \
        pji += __shfl_xor(pji, off, 64);                                     \
        pjj += __shfl_xor(pjj, off, 64);                                     \
    }                                                                        \
    const float mA = (kk < kend) ? 1.f : 0.f;                                \
    const float mI = (kk >= 1) ? mA : 0.f;                                   \
    const float cij = pij * INV_TAU, ci0 = pii * INV_TAU;                    \
    const float cji = pji * INV_TAU, ci1 = pjj * INV_TAU;                    \
    const float e3ij = __expf(cij * INV3), e3ji = __expf(cji * INV3);        \
    const float e3i0 = __expf(ci0 * INV3), e3i1 = __expf(ci1 * INV3);        \
    s1ij += mA * __expf(cij);                                                \
    s1ji += mA * __expf(cji);                                                \
    s3ij += mA * e3ij;                                                       \
    s3ji += mA * e3ji;                                                       \
    wa += mA * e3ji * (cji - cij);                                           \
    wb += mA * e3ij * (cij - cji);                                           \
    s1i0 += mI * __expf(ci0);                                                \
    s1i1 += mI * __expf(ci1);                                                \
    s3i0 += mI * e3i0;                                                       \
    s3i1 += mI * e3i1;                                                       \
    wc += mI * e3i1 * (ci1 - ci0);                                           \
    wd += mI * e3i0 * (ci0 - ci1);                                           \
    if (kk == 0 && l8 == 0) { sps[0] = cij; sps[2] = cji; }                  \
    if (kk == 1 && l8 == 0) { sps[1] = cij; sps[3] = cji;                    \
                              sps[4] = ci0; sps[5] = ci1; }                  \
} while (0)

    FETCH(0, A0, A1);
    for (int it = 0; it < 16; it += 2) {
        FETCH(it + 1, B0, B1);
        COMPUTE(it, A0, A1);
        FETCH(it + 2, A0, A1);
        COMPUTE(it + 1, B0, B1);
    }
    COMPUTE(16, A0, A1);

#undef FETCH
#undef COMPUTE

    float v[12] = {s1ij, s1ji, s1i0, s1i1, s3ij, s3ji, s3i0, s3i1, wa, wb, wc, wd};
    #pragma unroll
    for (int j = 0; j < 12; ++j) {
        v[j] += __shfl_xor(v[j], 8, 64);
        v[j] += __shfl_xor(v[j], 16, 64);
        v[j] += __shfl_xor(v[j], 32, 64);
    }
    if (lane == 0) {
        #pragma unroll
        for (int j = 0; j < 12; ++j) red[w][j] = v[j];
    }
    __syncthreads();
    float* outp = partials + (b * CHUNKS + c) * 20;
    if (tid < 12) outp[tid] = red[0][tid] + red[1][tid] + red[2][tid] + red[3][tid];
    else if (tid < 18) outp[tid] = sps[tid - 12];
}

__global__ void final_update(const float* __restrict__ partials, float* __restrict__ out,
                             const float* __restrict__ emb0, const float* __restrict__ emb1,
                             const float* __restrict__ mem0, const float* __restrict__ mem1,
                             const int* __restrict__ pos_idx,
                             float* __restrict__ o0, float* __restrict__ o1) {
    if (blockIdx.x < B) {
        const int b = blockIdx.x;
        const int tid = threadIdx.x;
        const int lane = tid & 63;
        const int net = tid >> 6;
        const int p0 = pos_idx[b * 2];
        bool skip = false;
        for (int b2 = b + 1; b2 < B; ++b2)
            if (pos_idx[b2 * 2] == p0) skip = true;
        if (skip) return;
        const float* mem = net ? mem1 : mem0;
        const float* emb = net ? emb1 : emb0;
        float* o = net ? o1 : o0;
        const float2 mv = *(const float2*)(mem + p0 * D + 2 * lane);
        const float2 ev = *(const float2*)(emb + b * D + 2 * lane);
        const float ux = 0.5f * mv.x + 0.5f * ev.x;
        const float uy = 0.5f * mv.y + 0.5f * ev.y;
        float ss = ux * ux + uy * uy;
        #pragma unroll
        for (int off = 1; off < 64; off <<= 1) ss += __shfl_xor(ss, off, 64);
        const float inv = 1.0f / sqrtf(ss);
        float2 wv; wv.x = ux * inv; wv.y = uy * inv;
        *(float2*)(o + p0 * D + 2 * lane) = wv;
        return;
    }
    const int b = threadIdx.x;
    float a[12];
    #pragma unroll
    for (int j = 0; j < 12; ++j) a[j] = 0.f;
    for (int c = 0; c < CHUNKS; ++c) {
        const float* p = partials + (b * CHUNKS + c) * 20;
        #pragma unroll
        for (int j = 0; j < 12; ++j) a[j] += p[j];
    }
    const float* e = partials + (b * CHUNKS) * 20 + 12;
    const float cij0 = e[0], cij1 = e[1], cji0 = e[2], cji1 = e[3], i01 = e[4], i11 = e[5];
    const float icl_b = -((cij0 + cij1) * 0.5f - __logf(a[0]))
                        - ((cji0 + cji1) * 0.5f - __logf(a[1]));
    const float vcl_b = -(i01 - __logf(a[2])) - (i11 - __logf(a[3]));
    const float sicl_b = 3.0f * (a[8] / a[5] + a[9] / a[4]);
    const float svcl_b = 3.0f * (a[10] / a[7] + a[11] / a[6]);
    __shared__ float r[4][128];
    r[0][b] = vcl_b; r[1][b] = svcl_b; r[2][b] = icl_b; r[3][b] = sicl_b;
    __syncthreads();
    for (int s = 64; s > 0; s >>= 1) {
        if (b < s) {
            r[0][b] += r[0][b + s]; r[1][b] += r[1][b + s];
            r[2][b] += r[2][b + s]; r[3][b] += r[3][b + s];
        }
        __syncthreads();
    }
    if (b == 0) {
        out[0] = r[0][0] * (1.0f / 128.f);
        out[1] = r[1][0] * (1.0f / 128.f);
        out[2] = r[2][0] * (1.0f / 128.f);
        out[3] = r[3][0] * (1.0f / 128.f);
    }
}

// mem copy: cached loads, non-temporal stores (write-once stream).
__global__ void copy_mems(const nt4* __restrict__ m0, const nt4* __restrict__ m1,
                          nt4* __restrict__ o0, nt4* __restrict__ o1) {
    for (int i = blockIdx.x * blockDim.x + threadIdx.x; i < N4; i += gridDim.x * blockDim.x) {
        nt4 a = m0[i];
        nt4 b = m1[i];
        __builtin_nontemporal_store(a, o0 + i);
        __builtin_nontemporal_store(b, o1 + i);
    }
}

extern "C" void kernel_launch(void* const* d_in, const int* in_sizes, int n_in,
                              void* d_out, int out_size, void* d_ws, size_t ws_size,
                              hipStream_t stream) {
    const float* emb0 = (const float*)d_in[0];
    const float* emb1 = (const float*)d_in[1];
    const float* mem0 = (const float*)d_in[2];
    const float* mem1 = (const float*)d_in[3];
    const int* pos_idx = (const int*)d_in[4];
    const int* neg_idx = (const int*)d_in[5];
    float* out = (float*)d_out;
    float* out_m0 = out + 4;
    float* out_m1 = out + 4 + NMEM * D;
    char* ws = (char*)d_ws;

    if (ws_size >= WS_NEED) {
        unsigned* cnt = (unsigned*)(ws + WS_CNT);
        unsigned* start = (unsigned*)(ws + WS_START);
        unsigned* entries = (unsigned*)(ws + WS_ENTRIES);
        float* partials_g = (float*)(ws + WS_PARTIALS);
        float* sp_g = (float*)(ws + WS_SP);

        zero_k<<<(NMEM + 255) / 256, 256, 0, stream>>>(cnt, partials_g, sp_g);
        hist_k<<<dim3((KTOT + 255) / 256, B), 256, 0, stream>>>(pos_idx, neg_idx, cnt);
        scan_k<<<1, 1024, 0, stream>>>(cnt, start, cnt);  // cnt becomes scatter cursors
        scatter_k<<<dim3((KTOT + 255) / 256, B), 256, 0, stream>>>(pos_idx, neg_idx,
                                                                   cnt, entries);
        main_gather<<<NBLK_MAIN, 256, 0, stream>>>(emb0, emb1, mem0, mem1,
                                                   start, entries, partials_g, sp_g);
        copy_mems<<<4096, 256, 0, stream>>>((const nt4*)mem0, (const nt4*)mem1,
                                            (nt4*)out_m0, (nt4*)out_m1);
        final2<<<B + 1, 128, 0, stream>>>(partials_g, sp_g, out, emb0, emb1,
                                          mem0, mem1, pos_idx, out_m0, out_m1);
    } else {
        // fallback: round-7 path (needs 160 KiB)
        float* partials = (float*)d_ws;
        gather_logits<<<dim3(CHUNKS, B), 256, 0, stream>>>(emb0, emb1, mem0, mem1,
                                                           pos_idx, neg_idx, partials);
        copy_mems<<<4096, 256, 0, stream>>>((const nt4*)mem0, (const nt4*)mem1,
                                            (nt4*)out_m0, (nt4*)out_m1);
        final_update<<<B + 1, 128, 0, stream>>>(partials, out, emb0, emb1,
                                                mem0, mem1, pos_idx, out_m0, out_m1);
    }
}